// Round 3
// baseline (347.687 us; speedup 1.0000x reference)
//
#include <hip/hip_runtime.h>

// BoxFilter (r=4): 9x9 clamped-window box SUM. Wave-streaming, float4/lane.
// Each wave: 62 active lanes x 4 cols = 248 input cols -> 240 output cols
// (1920 = 8 strips x 240). Streams SH=27 output rows (40 segments).
// Vertical 9-sum: register ring of float4 (static idx via 9-unrolled chunks).
// Horizontal 9-sum: per-lane prefix/suffix + 5 shuffles per 4 outputs.
//
// R3 change: PINNED depth-9 load pipeline via __builtin_amdgcn_sched_barrier(0).
// R1 (same-block batch) and R2 (loop-carried prefetch) were both undone by the
// compiler -- VGPR_Count stayed 48, i.e. the st[9] staging buffer was never
// live, loads were rescheduled back to depth-1 consume order. sched_barrier(0)
// is opaque to IR passes and the machine scheduler: loads issued in region n
// cannot sink past the barrier into their consume region n+1. Steady state:
// 9 loads (9 KB) in flight per wave across every region boundary ->
// progressive vmcnt(8..0) drains instead of load->wait->consume.
// __launch_bounds__(256,5) caps regalloc at ~102 VGPR (live set ~90).
// Hard-coded B=8,C=3,H=1080,W=1920,r=4.

#define W_IMG 1920
#define H_IMG 1080
#define SH 27          // output rows per segment (1080 = 40*27, 27%9==0)
#define R 4

typedef float f4 __attribute__((ext_vector_type(4)));

#define ROW_BODY(JJ, DO_PREFETCH)                                         \
    {                                                                     \
        const int row = row0 + chunk + (JJ) + R;   /* incoming row */     \
        f4 v = st[JJ];                                                    \
        if (DO_PREFETCH) {                         /* next chunk, slot JJ */\
            const int nrc = min(row + 9, H_IMG - 1);                      \
            st[JJ] = *(const f4*)(pcol + (long)nrc * W_IMG);              \
        }                                                                 \
        if (row >= H_IMG || !colOK) v = (f4){0.f, 0.f, 0.f, 0.f};         \
        vs += v;                                                          \
        ring[((JJ) + 8) % 9] = v;                                         \
                                                                          \
        /* Horizontal 9-sum over cols [cout .. cout+3]+[-4..+4] */        \
        const float s3 = vs.w;                 /* suffixes */             \
        const float s2 = vs.z + s3;                                       \
        const float s1 = vs.y + s2;                                       \
        const float S  = vs.x + s1;            /* full 4-sum */           \
        const float p2 = vs.x + vs.y;          /* prefixes */             \
        const float p3 = p2 + vs.z;                                       \
                                                                          \
        const float T  = __shfl_down(S, 1);    /* fullsum of lane+1 */    \
        const float q1 = __shfl_down(vs.x, 2); /* prefixes of lane+2 */   \
        const float q2 = __shfl_down(p2, 2);                              \
        const float q3 = __shfl_down(p3, 2);                              \
        const float q4 = __shfl_down(S, 2);                               \
                                                                          \
        f4 h;                                                             \
        h.x = S  + T + q1;                                                \
        h.y = s1 + T + q2;                                                \
        h.z = s2 + T + q3;                                                \
        h.w = s3 + T + q4;                                                \
        if (stOK) __builtin_nontemporal_store(h, (f4*)po);                \
        po += W_IMG;                                                      \
        vs -= ring[JJ];                        /* row leaving window */   \
    }

__global__ void __launch_bounds__(256, 5)
box9_wave4(const float* __restrict__ x, float* __restrict__ out) {
    const int lane  = threadIdx.x & 63;
    const int wv    = threadIdx.x >> 6;
    const int strip = blockIdx.x * 4 + wv;     // 0..7
    const int seg   = blockIdx.y;              // 0..39
    const int img   = blockIdx.z;              // 0..23
    const long base = (long)img * (H_IMG * W_IMG);

    // Lane l covers input cols cin_raw..cin_raw+3 (lane 0 = left halo).
    const int  cin_raw = strip * 240 - 4 + 4 * lane;
    const int  cin     = min(max(cin_raw, 0), W_IMG - 4);  // clamped (valid addr)
    const bool colOK   = (cin_raw >= 0) && (cin_raw + 3 < W_IMG);
    const int  cout    = strip * 240 + 4 * lane;
    const bool stOK    = (lane < 60);

    const int row0 = seg * SH;
    const float* pcol = x + base + cin;        // + row*W_IMG added per row
    float* po = out + base + (long)row0 * W_IMG + cout;

    f4 ring[9];
    f4 st[9];                                  // rotating prefetch buffer
    f4 vs = {0.f, 0.f, 0.f, 0.f};

    // Prologue: batch-issue 8 ring rows + 9 staged rows (17 loads in flight
    // before the first consume), then pin with a sched_barrier.
#pragma unroll
    for (int t = 0; t < 8; ++t) {
        const int rc = max(row0 - R + t, 0);          // lower clamp only
        ring[t] = *(const f4*)(pcol + (long)rc * W_IMG);
    }
#pragma unroll
    for (int j = 0; j < 9; ++j) {
        const int rc = min(row0 + j + R, H_IMG - 1);  // upper clamp only
        st[j] = *(const f4*)(pcol + (long)rc * W_IMG);
    }
    __builtin_amdgcn_sched_barrier(0);
#pragma unroll
    for (int t = 0; t < 8; ++t) {
        const int row = row0 - R + t;
        f4 v = ring[t];
        if (row < 0 || !colOK) v = (f4){0.f, 0.f, 0.f, 0.f};
        ring[t] = v;
        vs += v;
    }

    // Main: chunks with loop-carried prefetch; sched_barrier(0) closes each
    // region so this chunk's 9 prefetch loads cannot sink into the next
    // region where they are consumed.
#pragma unroll 1
    for (int chunk = 0; chunk < SH - 9; chunk += 9) {
#pragma unroll
        for (int j = 0; j < 9; ++j) ROW_BODY(j, true);
        __builtin_amdgcn_sched_barrier(0);
    }
    // Peeled last chunk: consume only, no prefetch (avoids 9 wasted loads).
    {
        const int chunk = SH - 9;
#pragma unroll
        for (int j = 0; j < 9; ++j) ROW_BODY(j, false);
    }
}

extern "C" void kernel_launch(void* const* d_in, const int* in_sizes, int n_in,
                              void* d_out, int out_size, void* d_ws, size_t ws_size,
                              hipStream_t stream) {
    const float* x = (const float*)d_in[0];
    float* out = (float*)d_out;
    // 8 strips (2 blocks x 4 waves), 40 row segments, 24 images
    dim3 grid(2, 40, 24);
    box9_wave4<<<grid, 256, 0, stream>>>(x, out);
}

// Round 4
// 346.311 us; speedup vs baseline: 1.0040x; 1.0040x over previous
//
#include <hip/hip_runtime.h>

// BoxFilter (r=4): 9x9 clamped-window box SUM. Wave-streaming, float4/lane.
// Each wave: 62 active lanes x 4 cols = 248 input cols -> 240 output cols
// (1920 = 8 strips x 240). Streams SH=27 output rows (40 segments).
// Vertical 9-sum: register ring of float4 (static idx via 9-unrolled chunks).
// Horizontal 9-sum: per-lane prefix/suffix + 5 shuffles per 4 outputs.
//
// R4 change: pin the depth-9 load pipeline with asm volatile("" ::: "memory").
// R1 (batch), R2 (loop-carried), R3 (sched_barrier) all failed the SAME way:
// VGPR_Count stayed 48 == no staging buffer live == loads sunk back to their
// consume points. sched_barrier(0) is IntrNoMem -- IR passes legally sink
// loads across it; only the machine scheduler respects it, too late.
// A memory clobber is opaque at IR *and* MIR level: no load or store may
// cross in either direction. The 9 prefetch loads of chunk n are therefore
// structurally pinned one full chunk before their consumes -> 9 KB in flight
// per wave, progressive vmcnt drains. VGPR_Count MUST rise to ~90; that is
// the mechanism check. Everything else byte-identical to R3.
// Hard-coded B=8,C=3,H=1080,W=1920,r=4.

#define W_IMG 1920
#define H_IMG 1080
#define SH 27          // output rows per segment (1080 = 40*27, 27%9==0)
#define R 4

#define PIPELINE_FENCE() asm volatile("" ::: "memory")

typedef float f4 __attribute__((ext_vector_type(4)));

#define ROW_BODY(JJ, DO_PREFETCH)                                         \
    {                                                                     \
        const int row = row0 + chunk + (JJ) + R;   /* incoming row */     \
        f4 v = st[JJ];                                                    \
        if (DO_PREFETCH) {                         /* next chunk, slot JJ */\
            const int nrc = min(row + 9, H_IMG - 1);                      \
            st[JJ] = *(const f4*)(pcol + (long)nrc * W_IMG);              \
        }                                                                 \
        if (row >= H_IMG || !colOK) v = (f4){0.f, 0.f, 0.f, 0.f};         \
        vs += v;                                                          \
        ring[((JJ) + 8) % 9] = v;                                         \
                                                                          \
        /* Horizontal 9-sum over cols [cout .. cout+3]+[-4..+4] */        \
        const float s3 = vs.w;                 /* suffixes */             \
        const float s2 = vs.z + s3;                                       \
        const float s1 = vs.y + s2;                                       \
        const float S  = vs.x + s1;            /* full 4-sum */           \
        const float p2 = vs.x + vs.y;          /* prefixes */             \
        const float p3 = p2 + vs.z;                                       \
                                                                          \
        const float T  = __shfl_down(S, 1);    /* fullsum of lane+1 */    \
        const float q1 = __shfl_down(vs.x, 2); /* prefixes of lane+2 */   \
        const float q2 = __shfl_down(p2, 2);                              \
        const float q3 = __shfl_down(p3, 2);                              \
        const float q4 = __shfl_down(S, 2);                               \
                                                                          \
        f4 h;                                                             \
        h.x = S  + T + q1;                                                \
        h.y = s1 + T + q2;                                                \
        h.z = s2 + T + q3;                                                \
        h.w = s3 + T + q4;                                                \
        if (stOK) __builtin_nontemporal_store(h, (f4*)po);                \
        po += W_IMG;                                                      \
        vs -= ring[JJ];                        /* row leaving window */   \
    }

__global__ void __launch_bounds__(256, 5)
box9_wave4(const float* __restrict__ x, float* __restrict__ out) {
    const int lane  = threadIdx.x & 63;
    const int wv    = threadIdx.x >> 6;
    const int strip = blockIdx.x * 4 + wv;     // 0..7
    const int seg   = blockIdx.y;              // 0..39
    const int img   = blockIdx.z;              // 0..23
    const long base = (long)img * (H_IMG * W_IMG);

    // Lane l covers input cols cin_raw..cin_raw+3 (lane 0 = left halo).
    const int  cin_raw = strip * 240 - 4 + 4 * lane;
    const int  cin     = min(max(cin_raw, 0), W_IMG - 4);  // clamped (valid addr)
    const bool colOK   = (cin_raw >= 0) && (cin_raw + 3 < W_IMG);
    const int  cout    = strip * 240 + 4 * lane;
    const bool stOK    = (lane < 60);

    const int row0 = seg * SH;
    const float* pcol = x + base + cin;        // + row*W_IMG added per row
    float* po = out + base + (long)row0 * W_IMG + cout;

    f4 ring[9];
    f4 st[9];                                  // rotating prefetch buffer
    f4 vs = {0.f, 0.f, 0.f, 0.f};

    // Prologue: batch-issue 8 ring rows + 9 staged rows (17 loads in flight
    // before the first consume), then pin with a full memory fence.
#pragma unroll
    for (int t = 0; t < 8; ++t) {
        const int rc = max(row0 - R + t, 0);          // lower clamp only
        ring[t] = *(const f4*)(pcol + (long)rc * W_IMG);
    }
#pragma unroll
    for (int j = 0; j < 9; ++j) {
        const int rc = min(row0 + j + R, H_IMG - 1);  // upper clamp only
        st[j] = *(const f4*)(pcol + (long)rc * W_IMG);
    }
    PIPELINE_FENCE();
#pragma unroll
    for (int t = 0; t < 8; ++t) {
        const int row = row0 - R + t;
        f4 v = ring[t];
        if (row < 0 || !colOK) v = (f4){0.f, 0.f, 0.f, 0.f};
        ring[t] = v;
        vs += v;
    }

    // Main: chunks with loop-carried prefetch; a memory fence closes each
    // region so this chunk's 9 prefetch loads cannot sink into the next
    // region where they are consumed (IR-level opaque, unlike sched_barrier).
#pragma unroll 1
    for (int chunk = 0; chunk < SH - 9; chunk += 9) {
#pragma unroll
        for (int j = 0; j < 9; ++j) ROW_BODY(j, true);
        PIPELINE_FENCE();
    }
    // Peeled last chunk: consume only, no prefetch (avoids 9 wasted loads).
    {
        const int chunk = SH - 9;
#pragma unroll
        for (int j = 0; j < 9; ++j) ROW_BODY(j, false);
    }
}

extern "C" void kernel_launch(void* const* d_in, const int* in_sizes, int n_in,
                              void* d_out, int out_size, void* d_ws, size_t ws_size,
                              hipStream_t stream) {
    const float* x = (const float*)d_in[0];
    float* out = (float*)d_out;
    // 8 strips (2 blocks x 4 waves), 40 row segments, 24 images
    dim3 grid(2, 40, 24);
    box9_wave4<<<grid, 256, 0, stream>>>(x, out);
}